// Round 8
// baseline (479.323 us; speedup 1.0000x reference)
//
#include <hip/hip_runtime.h>
#include <hip/hip_bf16.h>
#include <math.h>

// MOE: out[b,o] = sum_n gelu(x@gw^T+gb)[b,n] * (x @ W_n^T)[b,o]
// R8: xs pre-scale -> pure bf16 GEMM. Geometry chosen for INTER-BLOCK overlap
// (m114): BM=256 BN=128, 4 waves (2Mx2N) of 128x64, BK=32, dbuf LDS=48KB ->
// 2 blocks/CU. Simple 2-phase loop (stage next / read+MFMA / syncthreads),
// compiler-scheduled interior. 2-way-free LDS swizzle g^=(row>>1)&3 both sides.
// Split-K x4 via fp32 atomics into zeroed out.

#define BSZ  4096
#define NEXP 32
#define IDIM 1024
#define ODIM 1024

typedef unsigned short u16;
typedef __attribute__((ext_vector_type(8))) short bf16x8;
typedef __attribute__((ext_vector_type(4))) float f32x4;

#define GLOAD_LDS16(g, l) __builtin_amdgcn_global_load_lds( \
    (const __attribute__((address_space(1))) void*)(g),     \
    (__attribute__((address_space(3))) void*)(l), 16, 0, 0)

__device__ __forceinline__ u16 f2bf(float f) {
  unsigned u = __float_as_uint(f);
  return (u16)((u + 0x7FFFu + ((u >> 16) & 1u)) >> 16);  // RNE
}

// ---------------- zero d_out ----------------
__global__ void zero_kernel(float* __restrict__ out) {
  int i = blockIdx.x * blockDim.x + threadIdx.x;
  ((float4*)out)[i] = make_float4(0.f, 0.f, 0.f, 0.f);
}

// ---------------- fp32 -> bf16 conversion (8 elems/thread) ----------------
__global__ void conv_kernel(const float* __restrict__ in, u16* __restrict__ outb) {
  int i = blockIdx.x * blockDim.x + threadIdx.x;
  const float4* p = (const float4*)in + (size_t)i * 2;
  float4 a = p[0], b = p[1];
  union { bf16x8 v; u16 s[8]; } o;
  o.s[0] = f2bf(a.x); o.s[1] = f2bf(a.y); o.s[2] = f2bf(a.z); o.s[3] = f2bf(a.w);
  o.s[4] = f2bf(b.x); o.s[5] = f2bf(b.y); o.s[6] = f2bf(b.z); o.s[7] = f2bf(b.w);
  ((bf16x8*)outb)[i] = o.v;
}

// ---------------- gate: gT[n][b] = gelu(x[b]·gw[n] + gb[n]) ----------------
__global__ void gate_kernel(const float* __restrict__ x, const float* __restrict__ gw,
                            const float* __restrict__ gb, float* __restrict__ gT) {
  const int lane = threadIdx.x & 63;
  const int row = blockIdx.x * 4 + (threadIdx.x >> 6);
  const float4* xr = (const float4*)(x + (size_t)row * IDIM);
  float4 xv[4];
#pragma unroll
  for (int t = 0; t < 4; ++t) xv[t] = xr[t * 64 + lane];
  for (int n = 0; n < NEXP; ++n) {
    const float4* wr = (const float4*)(gw + (size_t)n * IDIM);
    float s = 0.f;
#pragma unroll
    for (int t = 0; t < 4; ++t) {
      float4 wv = wr[t * 64 + lane];
      s += xv[t].x * wv.x + xv[t].y * wv.y + xv[t].z * wv.z + xv[t].w * wv.w;
    }
#pragma unroll
    for (int off = 32; off > 0; off >>= 1) s += __shfl_down(s, off, 64);
    if (lane == 0) {
      float v = s + gb[n];
      gT[(size_t)n * BSZ + row] = 0.5f * v * (1.0f + erff(v * 0.70710678118f));
    }
  }
}

// ---------------- xs[e][b][i] = bf16(g[b, base+e] * x[b][i]) ----------------
__global__ void scale_kernel(const float* __restrict__ x, const float* __restrict__ gT,
                             u16* __restrict__ xs, int base) {
  int idx = blockIdx.x * 256 + threadIdx.x;
  int chunk = idx & 127;
  int b = (idx >> 7) & 4095;
  int e = idx >> 19;
  const float4* xp = (const float4*)(x + ((size_t)b << 10) + chunk * 8);
  float4 v0 = xp[0], v1 = xp[1];
  float g = gT[((size_t)(base + e) << 12) + b];
  union { bf16x8 v; u16 s[8]; } o;
  o.s[0] = f2bf(g * v0.x); o.s[1] = f2bf(g * v0.y);
  o.s[2] = f2bf(g * v0.z); o.s[3] = f2bf(g * v0.w);
  o.s[4] = f2bf(g * v1.x); o.s[5] = f2bf(g * v1.y);
  o.s[6] = f2bf(g * v1.z); o.s[7] = f2bf(g * v1.w);
  *(bf16x8*)&xs[((size_t)e << 22) + ((size_t)b << 10) + chunk * 8] = o.v;
}

// ---------------- main GEMM ----------------
// 512 blocks (2/CU), 256 threads (4 waves 2Mx2N, wave = 128x64 output).
// Block tile 256x128, BK=32 (one 16x16x32 K-step per kt). NKT = eps*32.
__global__ __launch_bounds__(256, 2) void gemm_kernel(
    const u16* __restrict__ xs,   // [EPR][4096][1024] bf16 (pre-scaled)
    const u16* __restrict__ wb,   // [EPR][1024][1024] bf16 (e,o,i)
    float* __restrict__ out,      // [4096][1024] fp32
    int eps)                      // experts per split (EPR/4)
{
  __shared__ u16 As[2][256 * 32];   // 2 x 16 KB
  __shared__ u16 Bs[2][128 * 32];   // 2 x  8 KB  (48 KB total -> 2 blocks/CU)

  const int tid  = threadIdx.x;
  const int lane = tid & 63;
  const int wid  = tid >> 6;     // 0..3
  const int wm   = wid >> 1;     // 0..1 (M)
  const int wn   = wid & 1;      // 0..1 (N)

  // XCD-chunked swizzle (512 % 8 == 0 -> bijective); mtile innermost so the
  // 64 blocks of one XCD-chunk share one split's W panel + xs slice.
  const int orig  = blockIdx.x;
  const int wgid  = (orig & 7) * 64 + (orig >> 3);
  const int mtile = wgid & 15;
  const int grp   = wgid >> 4;          // 0..31
  const int split = grp >> 3;           // 0..3
  const int ntile = grp & 7;            // 0..7
  const int row0  = mtile * 256;
  const int col0  = ntile * 128;

  // staging: per call (l, wid): granule index G = (l*4+wid)*64 + lane
  // row r = G>>2, LDS slot js = G&3, source granule = js ^ ((r>>1)&3)
  const int rsub = lane >> 2;    // 0..15 row within 16-row stripe
  const int js   = lane & 3;

  const int frow = lane & 15;
  const int hi   = lane >> 4;

  f32x4 acc[8][4];
#pragma unroll
  for (int i = 0; i < 8; ++i)
#pragma unroll
    for (int j = 0; j < 4; ++j) acc[i][j] = f32x4{0.f, 0.f, 0.f, 0.f};

  auto SA = [&](int buf, int kt, int l) {
    const int e  = split * eps + (kt >> 5);
    const int i0 = (kt & 31) << 5;
    const int r  = (l * 4 + wid) * 16 + rsub;
    const int sg = js ^ ((r >> 1) & 3);
    GLOAD_LDS16(xs + ((size_t)e << 22) + ((size_t)(row0 + r) << 10) + i0 + sg * 8,
                &As[buf][(l * 4 + wid) * 512]);
  };
  auto SB = [&](int buf, int kt, int l) {
    const int e  = split * eps + (kt >> 5);
    const int i0 = (kt & 31) << 5;
    const int r  = (l * 4 + wid) * 16 + rsub;
    const int sg = js ^ ((r >> 1) & 3);
    GLOAD_LDS16(wb + ((size_t)e << 20) + ((size_t)(col0 + r) << 10) + i0 + sg * 8,
                &Bs[buf][(l * 4 + wid) * 512]);
  };

  const int NKT = eps << 5;   // IDIM/BK = 32 kt per expert

  // prologue
#pragma unroll
  for (int l = 0; l < 4; ++l) SA(0, 0, l);
#pragma unroll
  for (int l = 0; l < 2; ++l) SB(0, 0, l);
  __syncthreads();   // full drain: tile 0 resident everywhere

  int cur = 0;
#pragma unroll 1
  for (int kt = 0; kt < NKT; ++kt) {
    if (kt + 1 < NKT) {
#pragma unroll
      for (int l = 0; l < 4; ++l) SA(cur ^ 1, kt + 1, l);
#pragma unroll
      for (int l = 0; l < 2; ++l) SB(cur ^ 1, kt + 1, l);
    }

    // fragments (swizzled read: slot = hi ^ ((r>>1)&3))
    bf16x8 a[8], b[4];
#pragma unroll
    for (int mi = 0; mi < 8; ++mi) {
      const int r = wm * 128 + mi * 16 + frow;
      a[mi] = *(const bf16x8*)&As[cur][r * 32 + (hi ^ ((r >> 1) & 3)) * 8];
    }
#pragma unroll
    for (int ni = 0; ni < 4; ++ni) {
      const int r = wn * 64 + ni * 16 + frow;
      b[ni] = *(const bf16x8*)&Bs[cur][r * 32 + (hi ^ ((r >> 1) & 3)) * 8];
    }

    // 32 independent MFMAs (compiler interleaves with lgkm waits)
#pragma unroll
    for (int mi = 0; mi < 8; ++mi)
#pragma unroll
      for (int ni = 0; ni < 4; ++ni)
        acc[mi][ni] = __builtin_amdgcn_mfma_f32_16x16x32_bf16(
            a[mi], b[ni], acc[mi][ni], 0, 0, 0);

    __syncthreads();   // drains vmcnt+lgkm: next buffer ready, this one free
    cur ^= 1;
  }

  // split-K contribution via atomics (out pre-zeroed)
  const int orow0 = row0 + wm * 128 + hi * 4;
  const int ocol0 = col0 + wn * 64 + frow;
#pragma unroll
  for (int mi = 0; mi < 8; ++mi)
#pragma unroll
    for (int j = 0; j < 4; ++j) {
      const int r = orow0 + mi * 16 + j;
#pragma unroll
      for (int ni = 0; ni < 4; ++ni)
        atomicAdd(out + (size_t)r * ODIM + ocol0 + ni * 16, acc[mi][ni][j]);
    }
}

extern "C" void kernel_launch(void* const* d_in, const int* in_sizes, int n_in,
                              void* d_out, int out_size, void* d_ws, size_t ws_size,
                              hipStream_t stream) {
  const float* x  = (const float*)d_in[0];   // [4096][1024]
  const float* w  = (const float*)d_in[1];   // [32][1024][1024]
  const float* gw = (const float*)d_in[2];   // [32][1024]
  const float* gb = (const float*)d_in[3];   // [32]
  float* out = (float*)d_out;                // [4096][1024]

  const size_t MiB = 1u << 20;
  int EPR;
  if      (ws_size >= 321 * MiB) EPR = 32;
  else if (ws_size >=  81 * MiB) EPR = 8;
  else                           EPR = 4;
  const int NR = NEXP / EPR;

  u16*   xs   = (u16*)d_ws;                                     // EPR * 8 MiB
  u16*   wbuf = (u16*)((char*)d_ws + (size_t)EPR * 8 * MiB);    // EPR * 2 MiB
  float* gT   = (float*)((char*)d_ws + (size_t)EPR * 10 * MiB); // 512 KiB

  zero_kernel<<<(BSZ * ODIM / 4) / 256, 256, 0, stream>>>(out);
  gate_kernel<<<BSZ / 4, 256, 0, stream>>>(x, gw, gb, gT);

  for (int r = 0; r < NR; ++r) {
    conv_kernel<<<EPR * 512, 256, 0, stream>>>(w + (size_t)r * EPR * IDIM * ODIM, wbuf);
    scale_kernel<<<EPR * 2048, 256, 0, stream>>>(x, gT, xs, r * EPR);
    gemm_kernel<<<512, 256, 0, stream>>>(xs, wbuf, out, EPR / 4);
  }
}